// Round 5
// baseline (520.439 us; speedup 1.0000x reference)
//
#include <hip/hip_runtime.h>

#define N_NODES 100000
#define N_EDGES 1600000
#define SCAN_B 1024
#define NB ((N_NODES + SCAN_B - 1) / SCAN_B)  // 98
#define P_PARTS 8
#define P_CHUNKS 32
#define PART_SZ 12500  // N_NODES / 8

__device__ __forceinline__ float bcast_lane(float v, int k) {
    return __int_as_float(__builtin_amdgcn_readlane(__float_as_int(v), k));
}

// ---- degree histogram: int4 loads, 4 independent fire-and-forget atomics ----
__global__ void k_count(const int* __restrict__ dst, int* __restrict__ deg) {
    int e = (blockIdx.x * blockDim.x + threadIdx.x) * 4;
    if (e + 3 < N_EDGES) {
        int4 d = *(const int4*)(dst + e);
        atomicAdd(&deg[d.x], 1);
        atomicAdd(&deg[d.y], 1);
        atomicAdd(&deg[d.z], 1);
        atomicAdd(&deg[d.w], 1);
    }
}

// ---- xs = z * dinv[row]  (float4 vectorized) ----
__global__ void k_scale(const float* __restrict__ z, const float* __restrict__ dinv,
                        float* __restrict__ xs) {
    int idx = blockIdx.x * blockDim.x + threadIdx.x;
    if (idx < N_NODES * 16) {
        float4 v = ((const float4*)z)[idx];
        float d = dinv[idx >> 4];
        v.x *= d; v.y *= d; v.z *= d; v.w *= d;
        ((float4*)xs)[idx] = v;
    }
}

// ---- scan phase 1 (+ fused dinv) ----
__global__ __launch_bounds__(SCAN_B) void k_scan1(const int* __restrict__ deg,
                                                  int* __restrict__ excl,
                                                  int* __restrict__ bsum,
                                                  float* __restrict__ dinv) {
    __shared__ int sm[SCAN_B];
    int t = threadIdx.x;
    int i = blockIdx.x * SCAN_B + t;
    int v = (i < N_NODES) ? deg[i] : 0;
    if (i < N_NODES) dinv[i] = rsqrtf((float)v + 1.0f);
    sm[t] = v;
    __syncthreads();
    for (int off = 1; off < SCAN_B; off <<= 1) {
        int u = (t >= off) ? sm[t - off] : 0;
        __syncthreads();
        sm[t] += u;
        __syncthreads();
    }
    if (i < N_NODES) excl[i] = sm[t] - v;
    if (t == SCAN_B - 1) bsum[blockIdx.x] = sm[t];
}

__global__ __launch_bounds__(128) void k_scan2(int* __restrict__ bsum) {
    __shared__ int sm[128];
    int t = threadIdx.x;
    int v = (t < NB) ? bsum[t] : 0;
    sm[t] = v;
    __syncthreads();
    for (int off = 1; off < 128; off <<= 1) {
        int u = (t >= off) ? sm[t - off] : 0;
        __syncthreads();
        sm[t] += u;
        __syncthreads();
    }
    if (t < NB) bsum[t] = sm[t] - v;
}

__global__ __launch_bounds__(SCAN_B) void k_scan3(int* __restrict__ rowptr,
                                                  int* __restrict__ cursor,
                                                  const int* __restrict__ bsum) {
    int i = blockIdx.x * SCAN_B + threadIdx.x;
    if (i < N_NODES) {
        int r = rowptr[i] + bsum[blockIdx.x];
        rowptr[i] = r;
        cursor[i] = r;
    }
    if (i == 0) rowptr[N_NODES] = N_EDGES;
}

// ---- XCD-local CSR placement at LOW concurrency (256 blocks).
//      part = bid&7 -> one XCD's L2 owns that part's col (800 KB) + cursor
//      (50 KB); dirty lines fill before eviction. Batched independent
//      atomic-rtns supply ILP since only ~1-4 waves/CU are resident. ----
__global__ __launch_bounds__(256) void k_place(const int* __restrict__ src,
                                               const int* __restrict__ dst,
                                               int* __restrict__ cursor,
                                               int* __restrict__ col) {
    unsigned part = blockIdx.x & 7;
    int chunk = blockIdx.x >> 3;
    const int CS = N_EDGES / P_CHUNKS;  // 50000
    int base = chunk * CS, lim = base + CS;
    for (int e = base + threadIdx.x; e < lim; e += 256 * 4) {
        int dd[4], ss[4], pp[4];
        bool mm[4];
#pragma unroll
        for (int i = 0; i < 4; ++i) {
            int ee = e + i * 256;
            bool ok = ee < lim;
            dd[i] = ok ? dst[ee] : -1;
            ss[i] = ok ? src[ee] : 0;
            mm[i] = ((unsigned)dd[i] / PART_SZ) == part;
        }
#pragma unroll
        for (int i = 0; i < 4; ++i)
            if (mm[i]) pp[i] = atomicAdd(&cursor[dd[i]], 1);
#pragma unroll
        for (int i = 0; i < 4; ++i)
            if (mm[i]) col[pp[i]] = ss[i];
    }
}

// ---- agg[n] = dinv[n]*(sum_{s in N(n)} xs[s] + xs[n]); dual node/wave,
//      8 independent gather chains, no W regs -> high occupancy. ----
__global__ __launch_bounds__(256) void k_agg(const int* __restrict__ rowptr,
                                             const int* __restrict__ col,
                                             const float* __restrict__ dinv,
                                             const float* __restrict__ xs,
                                             float* __restrict__ agg) {
    const int lane = threadIdx.x & 63;
    const int quarter = lane >> 4;
    const int fl = lane & 15;
    int wave = (blockIdx.x * blockDim.x + threadIdx.x) >> 6;
    int nwaves = (gridDim.x * blockDim.x) >> 6;

    for (int n0 = wave * 2; n0 < N_NODES; n0 += nwaves * 2) {
        int u0 = __builtin_amdgcn_readfirstlane(n0);
        int u1 = u0 + 1;
        bool has1 = (u1 < N_NODES);
        int beg0 = rowptr[u0], end0 = rowptr[u0 + 1];
        int beg1 = has1 ? rowptr[u1] : 0;
        int end1 = has1 ? rowptr[u1 + 1] : 0;
        int d0 = end0 - beg0, d1 = end1 - beg1;
        int iters = ((d0 > d1 ? d0 : d1) + 15) >> 4;
        int safe0 = d0 > 0 ? end0 - 1 : 0;
        int safe1 = d1 > 0 ? end1 - 1 : 0;

        float4 a0 = {0.f, 0.f, 0.f, 0.f};
        float4 a1 = {0.f, 0.f, 0.f, 0.f};
        for (int r = 0; r < iters; ++r) {
            int o = (r << 4) + quarter;
            int eA = beg0 + o, eB = eA + 4, eC = eA + 8, eD = eA + 12;
            int fA = beg1 + o, fB = fA + 4, fC = fA + 8, fD = fA + 12;
            int iA = col[eA < end0 ? eA : safe0];
            int iB = col[eB < end0 ? eB : safe0];
            int iC = col[eC < end0 ? eC : safe0];
            int iD = col[eD < end0 ? eD : safe0];
            int jA = col[fA < end1 ? fA : safe1];
            int jB = col[fB < end1 ? fB : safe1];
            int jC = col[fC < end1 ? fC : safe1];
            int jD = col[fD < end1 ? fD : safe1];
            float4 vA = *(const float4*)(xs + (size_t)iA * 64 + fl * 4);
            float4 vB = *(const float4*)(xs + (size_t)iB * 64 + fl * 4);
            float4 vC = *(const float4*)(xs + (size_t)iC * 64 + fl * 4);
            float4 vD = *(const float4*)(xs + (size_t)iD * 64 + fl * 4);
            float4 wA = *(const float4*)(xs + (size_t)jA * 64 + fl * 4);
            float4 wB = *(const float4*)(xs + (size_t)jB * 64 + fl * 4);
            float4 wC = *(const float4*)(xs + (size_t)jC * 64 + fl * 4);
            float4 wD = *(const float4*)(xs + (size_t)jD * 64 + fl * 4);
            if (eA < end0) { a0.x += vA.x; a0.y += vA.y; a0.z += vA.z; a0.w += vA.w; }
            if (eB < end0) { a0.x += vB.x; a0.y += vB.y; a0.z += vB.z; a0.w += vB.w; }
            if (eC < end0) { a0.x += vC.x; a0.y += vC.y; a0.z += vC.z; a0.w += vC.w; }
            if (eD < end0) { a0.x += vD.x; a0.y += vD.y; a0.z += vD.z; a0.w += vD.w; }
            if (fA < end1) { a1.x += wA.x; a1.y += wA.y; a1.z += wA.z; a1.w += wA.w; }
            if (fB < end1) { a1.x += wB.x; a1.y += wB.y; a1.z += wB.z; a1.w += wB.w; }
            if (fC < end1) { a1.x += wC.x; a1.y += wC.y; a1.z += wC.z; a1.w += wC.w; }
            if (fD < end1) { a1.x += wD.x; a1.y += wD.y; a1.z += wD.z; a1.w += wD.w; }
        }
#pragma unroll
        for (int m = 16; m <= 32; m <<= 1) {
            a0.x += __shfl_xor(a0.x, m, 64);
            a0.y += __shfl_xor(a0.y, m, 64);
            a0.z += __shfl_xor(a0.z, m, 64);
            a0.w += __shfl_xor(a0.w, m, 64);
            a1.x += __shfl_xor(a1.x, m, 64);
            a1.y += __shfl_xor(a1.y, m, 64);
            a1.z += __shfl_xor(a1.z, m, 64);
            a1.w += __shfl_xor(a1.w, m, 64);
        }
        // epilogue: self-loop + dinv scale, then store. After the butterfly all
        // 4 quarter-groups hold identical float4s per fl; quarter 0 stores node0,
        // quarter 1 stores node1 (16 float4 lanes each = full 256B row).
        float4 s0 = *(const float4*)(xs + (size_t)u0 * 64 + fl * 4);
        float di0 = dinv[u0];
        a0.x = (a0.x + s0.x) * di0; a0.y = (a0.y + s0.y) * di0;
        a0.z = (a0.z + s0.z) * di0; a0.w = (a0.w + s0.w) * di0;
        if (quarter == 0)
            *(float4*)(agg + (size_t)u0 * 64 + fl * 4) = a0;
        if (has1) {
            float4 s1 = *(const float4*)(xs + (size_t)u1 * 64 + fl * 4);
            float di1 = dinv[u1];
            a1.x = (a1.x + s1.x) * di1; a1.y = (a1.y + s1.y) * di1;
            a1.z = (a1.z + s1.z) * di1; a1.w = (a1.w + s1.w) * di1;
            if (quarter == 1)
                *(float4*)(agg + (size_t)u1 * 64 + fl * 4) = a1;
        }
    }
}

// ---- out = epi( agg @ W + b ); row-aligned, safe in-place (out may == agg) ----
__global__ __launch_bounds__(256) void k_mv(const float* agg, const float* __restrict__ W,
                                            const float* __restrict__ bias,
                                            const float* __restrict__ dinv,
                                            float* out, int hidden) {
    const int lane = threadIdx.x & 63;
    float wcol[64];
#pragma unroll
    for (int k = 0; k < 64; ++k) wcol[k] = W[k * 64 + lane];
    const float bv = bias[lane];
    int wave = (blockIdx.x * blockDim.x + threadIdx.x) >> 6;
    int nwaves = (gridDim.x * blockDim.x) >> 6;
    for (int row = wave; row < N_NODES; row += nwaves) {
        float xv = agg[(size_t)row * 64 + lane];
        float o0 = bv, o1 = 0.f;
#pragma unroll
        for (int k = 0; k < 64; k += 2) {
            o0 = fmaf(bcast_lane(xv, k), wcol[k], o0);
            o1 = fmaf(bcast_lane(xv, k + 1), wcol[k + 1], o1);
        }
        float o = o0 + o1;
        if (hidden) o = fmaxf(o, 0.f) * dinv[row];  // pre-scale for next gather
        out[(size_t)row * 64 + lane] = o;
    }
}

extern "C" void kernel_launch(void* const* d_in, const int* in_sizes, int n_in,
                              void* d_out, int out_size, void* d_ws, size_t ws_size,
                              hipStream_t stream) {
    const float* z  = (const float*)d_in[0];
    const int* src  = (const int*)d_in[1];
    const int* dst  = (const int*)d_in[2];
    const float* W1 = (const float*)d_in[3];
    const float* b1 = (const float*)d_in[4];
    const float* W2 = (const float*)d_in[5];
    const float* b2 = (const float*)d_in[6];
    const float* W3 = (const float*)d_in[7];
    const float* b3 = (const float*)d_in[8];
    float* out = (float*)d_out;

    char* p = (char*)d_ws;
    int*   deg    = (int*)p;    p += (size_t)512 << 10;
    float* dinv   = (float*)p;  p += (size_t)512 << 10;
    int*   rowptr = (int*)p;    p += (size_t)512 << 10;
    int*   cursor = (int*)p;    p += (size_t)512 << 10;
    int*   bsum   = (int*)p;    p += (size_t)4 << 10;
    int*   col    = (int*)p;    p += (size_t)8 << 20;
    float* buf0   = (float*)p;  p += (size_t)32 << 20;
    float* buf1   = (float*)p;

    const int gC = (N_EDGES / 4 + 255) / 256;
    const int gS = (N_NODES * 16 + 255) / 256;
    const int gA = 2048;

    // ---- CSR build (once; graph shared by all 3 layers) ----
    hipMemsetAsync(deg, 0, N_NODES * sizeof(int), stream);
    k_count<<<gC, 256, 0, stream>>>(dst, deg);
    k_scan1<<<NB, SCAN_B, 0, stream>>>(deg, rowptr, bsum, dinv);
    k_scan2<<<1, 128, 0, stream>>>(bsum);
    k_scan3<<<NB, SCAN_B, 0, stream>>>(rowptr, cursor, bsum);
    k_place<<<P_PARTS * P_CHUNKS, 256, 0, stream>>>(src, dst, cursor, col);

    // ---- xs0 = z * dinv ----
    k_scale<<<gS, 256, 0, stream>>>(z, dinv, buf0);

    // ---- 3 layers: agg (gather) + mv (streamed matvec, in-place) ----
    k_agg<<<gA, 256, 0, stream>>>(rowptr, col, dinv, buf0, buf1);
    k_mv <<<gA, 256, 0, stream>>>(buf1, W1, b1, dinv, buf1, 1);
    k_agg<<<gA, 256, 0, stream>>>(rowptr, col, dinv, buf1, buf0);
    k_mv <<<gA, 256, 0, stream>>>(buf0, W2, b2, dinv, buf0, 1);
    k_agg<<<gA, 256, 0, stream>>>(rowptr, col, dinv, buf0, buf1);
    k_mv <<<gA, 256, 0, stream>>>(buf1, W3, b3, dinv, out, 0);
}

// Round 6
// 428.170 us; speedup vs baseline: 1.2155x; 1.2155x over previous
//
#include <hip/hip_runtime.h>

#define N_NODES 100000
#define N_EDGES 1600000
#define SCAN_B 1024
#define NB ((N_NODES + SCAN_B - 1) / SCAN_B)  // 98
#define N_BUCKETS 128
#define BUCKET_NODES 782           // 128*782 = 100096 >= N_NODES
#define BKT_BLOCKS 512
#define COL_LDS 16384              // staging ints (64 KB); region mean ~12.5k

__device__ __forceinline__ float bcast_lane(float v, int k) {
    return __int_as_float(__builtin_amdgcn_readlane(__float_as_int(v), k));
}

// ---- degree histogram: int4 loads, 4 independent fire-and-forget atomics ----
__global__ void k_count(const int* __restrict__ dst, int* __restrict__ deg) {
    int e = (blockIdx.x * blockDim.x + threadIdx.x) * 4;
    if (e + 3 < N_EDGES) {
        int4 d = *(const int4*)(dst + e);
        atomicAdd(&deg[d.x], 1);
        atomicAdd(&deg[d.y], 1);
        atomicAdd(&deg[d.z], 1);
        atomicAdd(&deg[d.w], 1);
    }
}

// ---- xs = z * dinv[row]  (float4 vectorized) ----
__global__ void k_scale(const float* __restrict__ z, const float* __restrict__ dinv,
                        float* __restrict__ xs) {
    int idx = blockIdx.x * blockDim.x + threadIdx.x;
    if (idx < N_NODES * 16) {
        float4 v = ((const float4*)z)[idx];
        float d = dinv[idx >> 4];
        v.x *= d; v.y *= d; v.z *= d; v.w *= d;
        ((float4*)xs)[idx] = v;
    }
}

// ---- scan phase 1 (+ fused dinv) ----
__global__ __launch_bounds__(SCAN_B) void k_scan1(const int* __restrict__ deg,
                                                  int* __restrict__ excl,
                                                  int* __restrict__ bsum,
                                                  float* __restrict__ dinv) {
    __shared__ int sm[SCAN_B];
    int t = threadIdx.x;
    int i = blockIdx.x * SCAN_B + t;
    int v = (i < N_NODES) ? deg[i] : 0;
    if (i < N_NODES) dinv[i] = rsqrtf((float)v + 1.0f);
    sm[t] = v;
    __syncthreads();
    for (int off = 1; off < SCAN_B; off <<= 1) {
        int u = (t >= off) ? sm[t - off] : 0;
        __syncthreads();
        sm[t] += u;
        __syncthreads();
    }
    if (i < N_NODES) excl[i] = sm[t] - v;
    if (t == SCAN_B - 1) bsum[blockIdx.x] = sm[t];
}

__global__ __launch_bounds__(128) void k_scan2(int* __restrict__ bsum) {
    __shared__ int sm[128];
    int t = threadIdx.x;
    int v = (t < NB) ? bsum[t] : 0;
    sm[t] = v;
    __syncthreads();
    for (int off = 1; off < 128; off <<= 1) {
        int u = (t >= off) ? sm[t - off] : 0;
        __syncthreads();
        sm[t] += u;
        __syncthreads();
    }
    if (t < NB) bsum[t] = sm[t] - v;
}

__global__ __launch_bounds__(SCAN_B) void k_scan3(int* __restrict__ rowptr,
                                                  const int* __restrict__ bsum) {
    int i = blockIdx.x * SCAN_B + threadIdx.x;
    if (i < N_NODES) rowptr[i] += bsum[blockIdx.x];
    if (i == 0) rowptr[N_NODES] = N_EDGES;
}

// ---- bucket cursors start at each bucket's col-region base ----
__global__ void k_binit(const int* __restrict__ rowptr, int* __restrict__ bcur) {
    int t = threadIdx.x;
    if (t < N_BUCKETS) bcur[t] = rowptr[t * BUCKET_NODES < N_NODES ? t * BUCKET_NODES : N_NODES];
}

// ---- phase 1: bucket edges by dst/782 into ebuf (pairs), coalesced runs ----
__global__ __launch_bounds__(256) void k_bucket(const int* __restrict__ src,
                                                const int* __restrict__ dst,
                                                int* __restrict__ bcur,
                                                int2* __restrict__ ebuf) {
    __shared__ int cnt[N_BUCKETS], base_s[N_BUCKETS];
    const int CS = N_EDGES / BKT_BLOCKS;  // 3125
    int t = threadIdx.x;
    int beg = blockIdx.x * CS, end = beg + CS;
    for (int i = t; i < N_BUCKETS; i += 256) cnt[i] = 0;
    __syncthreads();
    for (int e = beg + t; e < end; e += 256)
        atomicAdd(&cnt[(unsigned)dst[e] / BUCKET_NODES], 1);
    __syncthreads();
    for (int i = t; i < N_BUCKETS; i += 256) {
        base_s[i] = atomicAdd(&bcur[i], cnt[i]);
        cnt[i] = 0;  // reuse as local cursor
    }
    __syncthreads();
    for (int e = beg + t; e < end; e += 256) {
        int d = dst[e], s = src[e];
        int b = (unsigned)d / BUCKET_NODES;
        int l = atomicAdd(&cnt[b], 1);
        ebuf[base_s[b] + l] = make_int2(s, d);
    }
}

// ---- phase 2: one block per bucket; bin region in LDS, stream out coalesced ----
__global__ __launch_bounds__(1024) void k_build(const int* __restrict__ rowptr,
                                                const int2* __restrict__ ebuf,
                                                int* __restrict__ col) {
    __shared__ int cur[BUCKET_NODES];
    __shared__ int cls[COL_LDS];
    int b = blockIdx.x, t = threadIdx.x;
    int nb = b * BUCKET_NODES;
    int ne = nb + BUCKET_NODES < N_NODES ? nb + BUCKET_NODES : N_NODES;
    int nn = ne - nb;
    int rstart = rowptr[nb];
    int rlen = rowptr[ne] - rstart;
    for (int i = t; i < nn; i += 1024) cur[i] = rowptr[nb + i] - rstart;
    __syncthreads();
    if (rlen <= COL_LDS) {
        for (int e = t; e < rlen; e += 1024) {
            int2 p = ebuf[rstart + e];
            int l = atomicAdd(&cur[p.y - nb], 1);
            cls[l] = p.x;
        }
        __syncthreads();
        for (int i = t; i < rlen; i += 1024) col[rstart + i] = cls[i];
    } else {  // statistically unreachable fallback
        for (int e = t; e < rlen; e += 1024) {
            int2 p = ebuf[rstart + e];
            int l = atomicAdd(&cur[p.y - nb], 1);
            col[rstart + l] = p.x;
        }
    }
}

// ---- fused layer: out = epi( dinv[d]*(sum_{s in N(d)} xs[s] + xs[d]) @ W + b )
//      One wave per node; 16 lanes x float4 per row; 16 edges/iter ->
//      4 independent gather chains. W column in 64 VGPRs. ----
__global__ __launch_bounds__(256) void k_layer(const int* __restrict__ rowptr,
                                               const int* __restrict__ col,
                                               const float* __restrict__ dinv,
                                               const float* __restrict__ xs,
                                               const float* __restrict__ W,
                                               const float* __restrict__ bias,
                                               float* __restrict__ out, int hidden) {
    const int lane = threadIdx.x & 63;
    const int quarter = lane >> 4;
    const int fl = lane & 15;

    float wcol[64];
#pragma unroll
    for (int k = 0; k < 64; ++k) wcol[k] = W[k * 64 + lane];
    const float bv = bias[lane];

    int wave = (blockIdx.x * blockDim.x + threadIdx.x) >> 6;
    int nwaves = (gridDim.x * blockDim.x) >> 6;

    for (int node = wave; node < N_NODES; node += nwaves) {
        int un = __builtin_amdgcn_readfirstlane(node);
        int beg = rowptr[un], end = rowptr[un + 1];

        float4 acc = {0.f, 0.f, 0.f, 0.f};
        for (int e = beg; e < end; e += 16) {
            int e0 = e + quarter, e1 = e0 + 4, e2 = e0 + 8, e3 = e0 + 12;
            int i0 = col[e0 < end ? e0 : end - 1];
            int i1 = col[e1 < end ? e1 : end - 1];
            int i2 = col[e2 < end ? e2 : end - 1];
            int i3 = col[e3 < end ? e3 : end - 1];
            float4 v0 = *(const float4*)(xs + (size_t)i0 * 64 + fl * 4);
            float4 v1 = *(const float4*)(xs + (size_t)i1 * 64 + fl * 4);
            float4 v2 = *(const float4*)(xs + (size_t)i2 * 64 + fl * 4);
            float4 v3 = *(const float4*)(xs + (size_t)i3 * 64 + fl * 4);
            if (e0 < end) { acc.x += v0.x; acc.y += v0.y; acc.z += v0.z; acc.w += v0.w; }
            if (e1 < end) { acc.x += v1.x; acc.y += v1.y; acc.z += v1.z; acc.w += v1.w; }
            if (e2 < end) { acc.x += v2.x; acc.y += v2.y; acc.z += v2.z; acc.w += v2.w; }
            if (e3 < end) { acc.x += v3.x; acc.y += v3.y; acc.z += v3.z; acc.w += v3.w; }
        }
#pragma unroll
        for (int m = 16; m <= 32; m <<= 1) {
            acc.x += __shfl_xor(acc.x, m, 64);
            acc.y += __shfl_xor(acc.y, m, 64);
            acc.z += __shfl_xor(acc.z, m, 64);
            acc.w += __shfl_xor(acc.w, m, 64);
        }
        float4 sv = *(const float4*)(xs + (size_t)un * 64 + fl * 4);
        float di = dinv[un];
        acc.x = (acc.x + sv.x) * di; acc.y = (acc.y + sv.y) * di;
        acc.z = (acc.z + sv.z) * di; acc.w = (acc.w + sv.w) * di;

        float o0 = bv, o1 = 0.f;
#pragma unroll
        for (int k = 0; k < 64; k += 2) {
            float c0 = ((k & 3) == 0) ? acc.x : acc.z;
            float c1 = (((k + 1) & 3) == 1) ? acc.y : acc.w;
            o0 = fmaf(bcast_lane(c0, k >> 2), wcol[k], o0);
            o1 = fmaf(bcast_lane(c1, (k + 1) >> 2), wcol[k + 1], o1);
        }
        float o = o0 + o1;
        if (hidden) o = fmaxf(o, 0.f) * di;  // pre-scale for next layer's gather
        out[(size_t)un * 64 + lane] = o;
    }
}

extern "C" void kernel_launch(void* const* d_in, const int* in_sizes, int n_in,
                              void* d_out, int out_size, void* d_ws, size_t ws_size,
                              hipStream_t stream) {
    const float* z  = (const float*)d_in[0];
    const int* src  = (const int*)d_in[1];
    const int* dst  = (const int*)d_in[2];
    const float* W1 = (const float*)d_in[3];
    const float* b1 = (const float*)d_in[4];
    const float* W2 = (const float*)d_in[5];
    const float* b2 = (const float*)d_in[6];
    const float* W3 = (const float*)d_in[7];
    const float* b3 = (const float*)d_in[8];
    float* out = (float*)d_out;

    char* p = (char*)d_ws;
    int*   deg    = (int*)p;    p += (size_t)512 << 10;
    float* dinv   = (float*)p;  p += (size_t)512 << 10;
    int*   rowptr = (int*)p;    p += (size_t)512 << 10;  // N_NODES+1
    int*   bcur   = (int*)p;    p += (size_t)4 << 10;    // 128 ints
    int*   bsum   = (int*)p;    p += (size_t)4 << 10;    // 98 ints
    int*   col    = (int*)p;    p += (size_t)8 << 20;    // 6.4 MB used
    int2*  ebuf   = (int2*)p;   p += (size_t)16 << 20;   // 12.8 MB used
    float* buf0   = (float*)p;  p += (size_t)32 << 20;   // 25.6 MB used
    float* buf1   = (float*)p;

    const int gC = (N_EDGES / 4 + 255) / 256;
    const int gS = (N_NODES * 16 + 255) / 256;
    const int gL = 2048;  // full-chip wave count for the gather

    // ---- CSR build: count -> scan -> bucket -> LDS-bin (all coalesced) ----
    hipMemsetAsync(deg, 0, N_NODES * sizeof(int), stream);
    k_count<<<gC, 256, 0, stream>>>(dst, deg);
    k_scan1<<<NB, SCAN_B, 0, stream>>>(deg, rowptr, bsum, dinv);
    k_scan2<<<1, 128, 0, stream>>>(bsum);
    k_scan3<<<NB, SCAN_B, 0, stream>>>(rowptr, bsum);
    k_binit<<<1, 128, 0, stream>>>(rowptr, bcur);
    k_bucket<<<BKT_BLOCKS, 256, 0, stream>>>(src, dst, bcur, ebuf);
    k_build<<<N_BUCKETS, 1024, 0, stream>>>(rowptr, ebuf, col);

    // ---- xs0 = z * dinv ----
    k_scale<<<gS, 256, 0, stream>>>(z, dinv, buf0);

    // ---- 3 fused layers ----
    k_layer<<<gL, 256, 0, stream>>>(rowptr, col, dinv, buf0, W1, b1, buf1, 1);
    k_layer<<<gL, 256, 0, stream>>>(rowptr, col, dinv, buf1, W2, b2, buf0, 1);
    k_layer<<<gL, 256, 0, stream>>>(rowptr, col, dinv, buf0, W3, b3, out, 0);
}

// Round 7
// 339.084 us; speedup vs baseline: 1.5348x; 1.2627x over previous
//
#include <hip/hip_runtime.h>

#define N_NODES 100000
#define N_EDGES 1600000
#define N_BUCKETS 256
#define BUCKET_NODES 391      // 256*391 = 100096 >= N_NODES
#define CAP_E 8192            // raw edges per bucket: mean 6250, sigma ~79
#define CAP_C 12288           // padded col slots per bucket: mean ~9300
#define BKT_BLOCKS 256
#define DUMMY N_NODES         // zero feature row

__device__ __forceinline__ float bcast_lane(float v, int k) {
    return __int_as_float(__builtin_amdgcn_readlane(__float_as_int(v), k));
}

// ---- phase 1: bucket edges by dst range into fixed segments.
//      packed int = src (17b) | local_dst (9b, <391) << 17. ----
__global__ __launch_bounds__(256) void k_bucket(const int* __restrict__ src,
                                                const int* __restrict__ dst,
                                                int* __restrict__ btot,
                                                int* __restrict__ ebuf) {
    __shared__ int cnt[N_BUCKETS], base_s[N_BUCKETS];
    const int CS = N_EDGES / BKT_BLOCKS;  // 6250
    int t = threadIdx.x;
    int beg = blockIdx.x * CS, end = beg + CS;
    for (int i = t; i < N_BUCKETS; i += 256) cnt[i] = 0;
    __syncthreads();
    for (int e = beg + t; e < end; e += 256)
        atomicAdd(&cnt[(unsigned)dst[e] / BUCKET_NODES], 1);
    __syncthreads();
    for (int i = t; i < N_BUCKETS; i += 256) {
        base_s[i] = atomicAdd(&btot[i], cnt[i]);
        cnt[i] = 0;  // reuse as local cursor
    }
    __syncthreads();
    for (int e = beg + t; e < end; e += 256) {
        int d = dst[e], s = src[e];
        int b = (unsigned)d / BUCKET_NODES;
        int l = atomicAdd(&cnt[b], 1);
        ebuf[b * CAP_E + base_s[b] + l] = s | ((d - b * BUCKET_NODES) << 17);
    }
}

// ---- phase 2: one block per bucket. LDS: degree count -> dinv -> pad-16
//      scan -> rowinfo -> bin col in LDS -> coalesced stream-out.
//      Fused: xs = z * dinv for this bucket's node range; block 0 zeros
//      the dummy feature row. ----
__global__ __launch_bounds__(512) void k_build(const int* __restrict__ btot,
                                               const int* __restrict__ ebuf,
                                               int* __restrict__ col,
                                               int2* __restrict__ rowinfo,
                                               float* __restrict__ dinv,
                                               const float* __restrict__ z,
                                               float* __restrict__ xs) {
    __shared__ int deg[BUCKET_NODES];
    __shared__ int cur[BUCKET_NODES];
    __shared__ int sm[512];
    __shared__ int cls[CAP_C];
    int b = blockIdx.x, t = threadIdx.x;
    int nb = b * BUCKET_NODES;
    int nn = N_NODES - nb < BUCKET_NODES ? N_NODES - nb : BUCKET_NODES;
    int ne = btot[b];
    const int* eb = ebuf + b * CAP_E;

    for (int i = t; i < BUCKET_NODES; i += 512) deg[i] = 0;
    __syncthreads();
    for (int e = t; e < ne; e += 512) atomicAdd(&deg[eb[e] >> 17], 1);
    __syncthreads();

    // pad-to-16 lengths, inclusive Hillis-Steele scan over 512 slots
    int v = (t < nn) ? ((deg[t] + 15) & ~15) : 0;
    sm[t] = v;
    __syncthreads();
    for (int off = 1; off < 512; off <<= 1) {
        int u = (t >= off) ? sm[t - off] : 0;
        __syncthreads();
        sm[t] += u;
        __syncthreads();
    }
    int total = sm[511];
    int colbase = b * CAP_C;
    if (t < nn) {
        int off0 = sm[t] - v;
        cur[t] = off0;
        rowinfo[nb + t] = make_int2(colbase + off0, v);
        dinv[nb + t] = rsqrtf((float)deg[t] + 1.0f);
    }
    __syncthreads();
    for (int i = t; i < total; i += 512) cls[i] = DUMMY;  // pads pre-filled
    __syncthreads();
    for (int e = t; e < ne; e += 512) {
        int pe = eb[e];
        int l = atomicAdd(&cur[pe >> 17], 1);
        cls[l] = pe & 0x1FFFF;
    }
    __syncthreads();
    for (int i = t; i < total; i += 512) col[colbase + i] = cls[i];

    // fused scale: xs rows for this bucket (dinv recomputed from LDS deg)
    const float4* zz = (const float4*)(z + (size_t)nb * 64);
    float4* xx = (float4*)(xs + (size_t)nb * 64);
    for (int i = t; i < nn * 16; i += 512) {
        float4 vv = zz[i];
        float dd = rsqrtf((float)deg[i >> 4] + 1.0f);
        vv.x *= dd; vv.y *= dd; vv.z *= dd; vv.w *= dd;
        xx[i] = vv;
    }
    if (b == 0 && t < 16)  // zero the dummy row once
        ((float4*)(xs + (size_t)N_NODES * 64))[t] = make_float4(0.f, 0.f, 0.f, 0.f);
}

// ---- fused layer: out = epi( dinv[d]*(sum_{s in row(d)} xs[s] + xs[d]) @ W + b )
//      Rows padded to x16 with DUMMY (zero row): branch-free inner loop,
//      indices via one int4 load, 4 gather chains in flight. ----
__global__ __launch_bounds__(256) void k_layer(const int2* __restrict__ rowinfo,
                                               const int* __restrict__ col,
                                               const float* __restrict__ dinv,
                                               const float* __restrict__ xs,
                                               const float* __restrict__ W,
                                               const float* __restrict__ bias,
                                               float* __restrict__ out, int hidden) {
    const int lane = threadIdx.x & 63;
    const int quarter = lane >> 4;
    const int fl = lane & 15;

    float wcol[64];
#pragma unroll
    for (int k = 0; k < 64; ++k) wcol[k] = W[k * 64 + lane];
    const float bv = bias[lane];

    int wave = (blockIdx.x * blockDim.x + threadIdx.x) >> 6;
    int nwaves = (gridDim.x * blockDim.x) >> 6;

    for (int node = wave; node < N_NODES; node += nwaves) {
        int un = __builtin_amdgcn_readfirstlane(node);
        int2 ri = rowinfo[un];
        int beg = ri.x, end = ri.x + ri.y;

        float4 acc = {0.f, 0.f, 0.f, 0.f};
        for (int e = beg; e < end; e += 16) {
            int4 ii = *(const int4*)(col + e + 4 * quarter);
            float4 v0 = *(const float4*)(xs + (size_t)ii.x * 64 + fl * 4);
            float4 v1 = *(const float4*)(xs + (size_t)ii.y * 64 + fl * 4);
            float4 v2 = *(const float4*)(xs + (size_t)ii.z * 64 + fl * 4);
            float4 v3 = *(const float4*)(xs + (size_t)ii.w * 64 + fl * 4);
            acc.x += (v0.x + v1.x) + (v2.x + v3.x);
            acc.y += (v0.y + v1.y) + (v2.y + v3.y);
            acc.z += (v0.z + v1.z) + (v2.z + v3.z);
            acc.w += (v0.w + v1.w) + (v2.w + v3.w);
        }
#pragma unroll
        for (int m = 16; m <= 32; m <<= 1) {
            acc.x += __shfl_xor(acc.x, m, 64);
            acc.y += __shfl_xor(acc.y, m, 64);
            acc.z += __shfl_xor(acc.z, m, 64);
            acc.w += __shfl_xor(acc.w, m, 64);
        }
        float4 sv = *(const float4*)(xs + (size_t)un * 64 + fl * 4);
        float di = dinv[un];
        acc.x = (acc.x + sv.x) * di; acc.y = (acc.y + sv.y) * di;
        acc.z = (acc.z + sv.z) * di; acc.w = (acc.w + sv.w) * di;

        float o0 = bv, o1 = 0.f;
#pragma unroll
        for (int k = 0; k < 64; k += 2) {
            float c0 = ((k & 3) == 0) ? acc.x : acc.z;
            float c1 = (((k + 1) & 3) == 1) ? acc.y : acc.w;
            o0 = fmaf(bcast_lane(c0, k >> 2), wcol[k], o0);
            o1 = fmaf(bcast_lane(c1, (k + 1) >> 2), wcol[k + 1], o1);
        }
        float o = o0 + o1;
        if (hidden) o = fmaxf(o, 0.f) * di;  // pre-scale for next layer's gather
        out[(size_t)un * 64 + lane] = o;

        if (hidden && un == 0 && quarter == 0)  // keep dummy row zero for next gather
            *(float4*)(out + (size_t)N_NODES * 64 + fl * 4) = make_float4(0.f, 0.f, 0.f, 0.f);
    }
}

extern "C" void kernel_launch(void* const* d_in, const int* in_sizes, int n_in,
                              void* d_out, int out_size, void* d_ws, size_t ws_size,
                              hipStream_t stream) {
    const float* z  = (const float*)d_in[0];
    const int* src  = (const int*)d_in[1];
    const int* dst  = (const int*)d_in[2];
    const float* W1 = (const float*)d_in[3];
    const float* b1 = (const float*)d_in[4];
    const float* W2 = (const float*)d_in[5];
    const float* b2 = (const float*)d_in[6];
    const float* W3 = (const float*)d_in[7];
    const float* b3 = (const float*)d_in[8];
    float* out = (float*)d_out;

    char* p = (char*)d_ws;
    float* dinv    = (float*)p;  p += (size_t)512 << 10;
    int2*  rowinfo = (int2*)p;   p += (size_t)1 << 20;                    // 800 KB used
    int*   btot    = (int*)p;    p += (size_t)4 << 10;                    // 1 KB used
    int*   ebuf    = (int*)p;    p += (size_t)N_BUCKETS * CAP_E * 4;      // 8 MB
    int*   col     = (int*)p;    p += (size_t)N_BUCKETS * CAP_C * 4;      // 12.6 MB
    float* buf0    = (float*)p;  p += (size_t)26 << 20;                   // 100001 rows
    float* buf1    = (float*)p;                                           // 100001 rows

    const int gL = 2048;  // 8192 waves = full chip

    // ---- CSR build + scale: 3 dispatches total ----
    hipMemsetAsync(btot, 0, N_BUCKETS * sizeof(int), stream);
    k_bucket<<<BKT_BLOCKS, 256, 0, stream>>>(src, dst, btot, ebuf);
    k_build<<<N_BUCKETS, 512, 0, stream>>>(btot, ebuf, col, rowinfo, dinv, z, buf0);

    // ---- 3 fused layers ----
    k_layer<<<gL, 256, 0, stream>>>(rowinfo, col, dinv, buf0, W1, b1, buf1, 1);
    k_layer<<<gL, 256, 0, stream>>>(rowinfo, col, dinv, buf1, W2, b2, buf0, 1);
    k_layer<<<gL, 256, 0, stream>>>(rowinfo, col, dinv, buf0, W3, b3, out, 0);
}

// Round 8
// 325.694 us; speedup vs baseline: 1.5979x; 1.0411x over previous
//
#include <hip/hip_runtime.h>
#include <hip/hip_fp16.h>

#define N_NODES 100000
#define N_EDGES 1600000
#define N_BUCKETS 256
#define BUCKET_NODES 391      // 256*391 = 100096 >= N_NODES
#define CAP_E 8192            // raw edges per bucket: mean 6250
#define CAP_C 12288           // padded col slots per bucket: mean ~9300
#define BKT_BLOCKS 256
#define DUMMY N_NODES         // zero feature row

typedef unsigned short u16;

__device__ __forceinline__ float bcast_lane(float v, int k) {
    return __int_as_float(__builtin_amdgcn_readlane(__float_as_int(v), k));
}

__device__ __forceinline__ u16 f2h(float f) {
    return __half_as_ushort(__float2half_rn(f));
}

__device__ __forceinline__ void acc8(float* acc, uint4 q) {
    acc[0] += __half2float(__ushort_as_half((u16)(q.x & 0xffff)));
    acc[1] += __half2float(__ushort_as_half((u16)(q.x >> 16)));
    acc[2] += __half2float(__ushort_as_half((u16)(q.y & 0xffff)));
    acc[3] += __half2float(__ushort_as_half((u16)(q.y >> 16)));
    acc[4] += __half2float(__ushort_as_half((u16)(q.z & 0xffff)));
    acc[5] += __half2float(__ushort_as_half((u16)(q.z >> 16)));
    acc[6] += __half2float(__ushort_as_half((u16)(q.w & 0xffff)));
    acc[7] += __half2float(__ushort_as_half((u16)(q.w >> 16)));
}

// ---- phase 1: bucket edges by dst range into fixed segments.
//      packed int = src (17b) | local_dst (9b, <391) << 17. ----
__global__ __launch_bounds__(256) void k_bucket(const int* __restrict__ src,
                                                const int* __restrict__ dst,
                                                int* __restrict__ btot,
                                                int* __restrict__ ebuf) {
    __shared__ int cnt[N_BUCKETS], base_s[N_BUCKETS];
    const int CS = N_EDGES / BKT_BLOCKS;  // 6250
    int t = threadIdx.x;
    int beg = blockIdx.x * CS, end = beg + CS;
    for (int i = t; i < N_BUCKETS; i += 256) cnt[i] = 0;
    __syncthreads();
    for (int e = beg + t; e < end; e += 256)
        atomicAdd(&cnt[(unsigned)dst[e] / BUCKET_NODES], 1);
    __syncthreads();
    for (int i = t; i < N_BUCKETS; i += 256) {
        base_s[i] = atomicAdd(&btot[i], cnt[i]);
        cnt[i] = 0;  // reuse as local cursor
    }
    __syncthreads();
    for (int e = beg + t; e < end; e += 256) {
        int d = dst[e], s = src[e];
        int b = (unsigned)d / BUCKET_NODES;
        int l = atomicAdd(&cnt[b], 1);
        ebuf[b * CAP_E + base_s[b] + l] = s | ((d - b * BUCKET_NODES) << 17);
    }
}

// ---- phase 2: one block per bucket: LDS degree count -> dinv -> pad-16
//      scan -> rowinfo -> LDS col bin -> coalesced stream-out.
//      Fused: xs(fp16) = z * dinv for this bucket; block 0 zeros both
//      dummy feature rows. ----
__global__ __launch_bounds__(512) void k_build(const int* __restrict__ btot,
                                               const int* __restrict__ ebuf,
                                               int* __restrict__ col,
                                               int2* __restrict__ rowinfo,
                                               float* __restrict__ dinv,
                                               const float* __restrict__ z,
                                               u16* __restrict__ xs,
                                               u16* __restrict__ xs_other) {
    __shared__ int deg[BUCKET_NODES];
    __shared__ int cur[BUCKET_NODES];
    __shared__ int sm[512];
    __shared__ int cls[CAP_C];
    int b = blockIdx.x, t = threadIdx.x;
    int nb = b * BUCKET_NODES;
    int nn = N_NODES - nb < BUCKET_NODES ? N_NODES - nb : BUCKET_NODES;
    int ne = btot[b];
    const int* eb = ebuf + b * CAP_E;

    for (int i = t; i < BUCKET_NODES; i += 512) deg[i] = 0;
    __syncthreads();
    for (int e = t; e < ne; e += 512) atomicAdd(&deg[eb[e] >> 17], 1);
    __syncthreads();

    // pad-to-16 lengths, inclusive Hillis-Steele scan over 512 slots
    int v = (t < nn) ? ((deg[t] + 15) & ~15) : 0;
    sm[t] = v;
    __syncthreads();
    for (int off = 1; off < 512; off <<= 1) {
        int u = (t >= off) ? sm[t - off] : 0;
        __syncthreads();
        sm[t] += u;
        __syncthreads();
    }
    int total = sm[511];
    int colbase = b * CAP_C;
    if (t < nn) {
        int off0 = sm[t] - v;
        cur[t] = off0;
        rowinfo[nb + t] = make_int2(colbase + off0, v);
        dinv[nb + t] = rsqrtf((float)deg[t] + 1.0f);
    }
    __syncthreads();
    for (int i = t; i < total; i += 512) cls[i] = DUMMY;  // pads pre-filled
    __syncthreads();
    for (int e = t; e < ne; e += 512) {
        int pe = eb[e];
        int l = atomicAdd(&cur[pe >> 17], 1);
        cls[l] = pe & 0x1FFFF;
    }
    __syncthreads();
    for (int i = t; i < total; i += 512) col[colbase + i] = cls[i];

    // fused scale: xs(fp16) = z * dinv for this bucket's rows
    const float4* zz = (const float4*)(z + (size_t)nb * 64);
    uint2* xx = (uint2*)(xs + (size_t)nb * 64);
    for (int i = t; i < nn * 16; i += 512) {
        float4 vv = zz[i];
        float dd = rsqrtf((float)deg[i >> 4] + 1.0f);
        unsigned p0 = (unsigned)f2h(vv.x * dd) | ((unsigned)f2h(vv.y * dd) << 16);
        unsigned p1 = (unsigned)f2h(vv.z * dd) | ((unsigned)f2h(vv.w * dd) << 16);
        xx[i] = make_uint2(p0, p1);
    }
    if (b == 0 && t < 8) {  // zero dummy rows of both fp16 feature buffers
        ((uint4*)(xs + (size_t)N_NODES * 64))[t] = make_uint4(0, 0, 0, 0);
        ((uint4*)(xs_other + (size_t)N_NODES * 64))[t] = make_uint4(0, 0, 0, 0);
    }
}

// ---- fused layer: h = dinv[d]*(sum_{s in row(d)} xs[s] + xs[d]);
//      out = epi(h @ W + b). fp16 feature rows (128 B = 8 lanes x uint4),
//      8 lane-groups -> 2 gathers/lane per 16 slots; fp32 accumulate. ----
__global__ __launch_bounds__(256) void k_layer(const int2* __restrict__ rowinfo,
                                               const int* __restrict__ col,
                                               const float* __restrict__ dinv,
                                               const u16* __restrict__ xs,
                                               const float* __restrict__ W,
                                               const float* __restrict__ bias,
                                               u16* __restrict__ outh,
                                               float* __restrict__ outf,
                                               int hidden) {
    const int lane = threadIdx.x & 63;
    const int eighth = lane >> 3;   // slot pair selector within 16-slot iter
    const int fh = lane & 7;        // which uint4 (8 features) of the row

    float wcol[64];
#pragma unroll
    for (int k = 0; k < 64; ++k) wcol[k] = W[k * 64 + lane];
    const float bv = bias[lane];

    int wave = (blockIdx.x * blockDim.x + threadIdx.x) >> 6;
    int nwaves = (gridDim.x * blockDim.x) >> 6;

    for (int node = wave; node < N_NODES; node += nwaves) {
        int un = __builtin_amdgcn_readfirstlane(node);
        int2 ri = rowinfo[un];
        int beg = ri.x, end = ri.x + ri.y;

        float acc[8] = {0.f, 0.f, 0.f, 0.f, 0.f, 0.f, 0.f, 0.f};
        for (int e = beg; e < end; e += 16) {
            int2 ii = *(const int2*)(col + e + 2 * eighth);
            uint4 qa = *(const uint4*)(xs + (size_t)ii.x * 64 + fh * 8);
            uint4 qb = *(const uint4*)(xs + (size_t)ii.y * 64 + fh * 8);
            acc8(acc, qa);
            acc8(acc, qb);
        }
        // butterfly-reduce the 8 group partials (feature slot fh identical)
#pragma unroll
        for (int m = 8; m <= 32; m <<= 1) {
#pragma unroll
            for (int j = 0; j < 8; ++j) acc[j] += __shfl_xor(acc[j], m, 64);
        }
        // self-loop + dinv scale
        {
            uint4 qs = *(const uint4*)(xs + (size_t)un * 64 + fh * 8);
            float s[8] = {0.f, 0.f, 0.f, 0.f, 0.f, 0.f, 0.f, 0.f};
            acc8(s, qs);
            float di = dinv[un];
#pragma unroll
            for (int j = 0; j < 8; ++j) acc[j] = (acc[j] + s[j]) * di;
        }
        // matvec: o[lane] = sum_k h[k]*W[k][lane] + b ; h[k] on lane k>>3, slot k&7
        float o0 = bv, o1 = 0.f;
#pragma unroll
        for (int k = 0; k < 64; k += 2) {
            o0 = fmaf(bcast_lane(acc[k & 7], k >> 3), wcol[k], o0);
            o1 = fmaf(bcast_lane(acc[(k + 1) & 7], (k + 1) >> 3), wcol[k + 1], o1);
        }
        float o = o0 + o1;
        if (hidden) {
            o = fmaxf(o, 0.f) * dinv[un];  // pre-scale for next layer's gather
            outh[(size_t)un * 64 + lane] = f2h(o);
        } else {
            outf[(size_t)un * 64 + lane] = o;
        }
    }
}

extern "C" void kernel_launch(void* const* d_in, const int* in_sizes, int n_in,
                              void* d_out, int out_size, void* d_ws, size_t ws_size,
                              hipStream_t stream) {
    const float* z  = (const float*)d_in[0];
    const int* src  = (const int*)d_in[1];
    const int* dst  = (const int*)d_in[2];
    const float* W1 = (const float*)d_in[3];
    const float* b1 = (const float*)d_in[4];
    const float* W2 = (const float*)d_in[5];
    const float* b2 = (const float*)d_in[6];
    const float* W3 = (const float*)d_in[7];
    const float* b3 = (const float*)d_in[8];
    float* out = (float*)d_out;

    char* p = (char*)d_ws;
    float* dinv    = (float*)p;  p += (size_t)512 << 10;
    int2*  rowinfo = (int2*)p;   p += (size_t)1 << 20;                    // 800 KB used
    int*   btot    = (int*)p;    p += (size_t)4 << 10;
    int*   ebuf    = (int*)p;    p += (size_t)N_BUCKETS * CAP_E * 4;      // 8 MB
    int*   col     = (int*)p;    p += (size_t)N_BUCKETS * CAP_C * 4;      // 12.6 MB
    u16*   buf0    = (u16*)p;    p += (size_t)14 << 20;                   // 12.8 MB used
    u16*   buf1    = (u16*)p;                                             // 12.8 MB

    const int gL = 2048;  // 8192 waves = full chip

    // ---- CSR build + fp16 scale: 3 dispatches ----
    hipMemsetAsync(btot, 0, N_BUCKETS * sizeof(int), stream);
    k_bucket<<<BKT_BLOCKS, 256, 0, stream>>>(src, dst, btot, ebuf);
    k_build<<<N_BUCKETS, 512, 0, stream>>>(btot, ebuf, col, rowinfo, dinv, z, buf0, buf1);

    // ---- 3 fused layers ----
    k_layer<<<gL, 256, 0, stream>>>(rowinfo, col, dinv, buf0, W1, b1, buf1, nullptr, 1);
    k_layer<<<gL, 256, 0, stream>>>(rowinfo, col, dinv, buf1, W2, b2, buf0, nullptr, 1);
    k_layer<<<gL, 256, 0, stream>>>(rowinfo, col, dinv, buf0, W3, b3, nullptr, out, 0);
}

// Round 9
// 323.085 us; speedup vs baseline: 1.6108x; 1.0081x over previous
//
#include <hip/hip_runtime.h>
#include <hip/hip_fp16.h>

#define N_NODES 100000
#define N_EDGES 1600000
#define N_BUCKETS 256
#define BUCKET_NODES 391      // 256*391 = 100096 >= N_NODES
#define CAP_E 8192            // raw edges per bucket: mean 6250
#define CAP_C 12288           // padded col slots per bucket: mean ~9300
#define BKT_BLOCKS 512
#define DUMMY N_NODES         // zero feature row

typedef unsigned short u16;

__device__ __forceinline__ float bcast_lane(float v, int k) {
    return __int_as_float(__builtin_amdgcn_readlane(__float_as_int(v), k));
}

__device__ __forceinline__ u16 f2h(float f) {
    return __half_as_ushort(__float2half_rn(f));
}

__device__ __forceinline__ void acc8(float* acc, uint4 q) {
    unsigned v[4] = {q.x, q.y, q.z, q.w};
#pragma unroll
    for (int i = 0; i < 4; ++i) {
        __half2 h = *reinterpret_cast<__half2*>(&v[i]);
        float2 f = __half22float2(h);
        acc[2 * i] += f.x;
        acc[2 * i + 1] += f.y;
    }
}

// ---- phase 1: bucket edges by dst range into fixed segments.
//      packed int = src (17b) | local_dst (9b, <391) << 17. ----
__global__ __launch_bounds__(256) void k_bucket(const int* __restrict__ src,
                                                const int* __restrict__ dst,
                                                int* __restrict__ btot,
                                                int* __restrict__ ebuf) {
    __shared__ int cnt[N_BUCKETS], base_s[N_BUCKETS];
    const int CS = N_EDGES / BKT_BLOCKS;  // 3125
    int t = threadIdx.x;
    int beg = blockIdx.x * CS, end = beg + CS;
    for (int i = t; i < N_BUCKETS; i += 256) cnt[i] = 0;
    __syncthreads();
    for (int e = beg + t; e < end; e += 256)
        atomicAdd(&cnt[(unsigned)dst[e] / BUCKET_NODES], 1);
    __syncthreads();
    for (int i = t; i < N_BUCKETS; i += 256) {
        base_s[i] = atomicAdd(&btot[i], cnt[i]);
        cnt[i] = 0;  // reuse as local cursor
    }
    __syncthreads();
    for (int e = beg + t; e < end; e += 256) {
        int d = dst[e], s = src[e];
        int b = (unsigned)d / BUCKET_NODES;
        int l = atomicAdd(&cnt[b], 1);
        ebuf[b * CAP_E + base_s[b] + l] = s | ((d - b * BUCKET_NODES) << 17);
    }
}

// ---- phase 2: one block per bucket (1024 thr): LDS degree count -> dinv ->
//      pad-16 scan -> rowinfo -> LDS col bin -> coalesced stream-out.
//      Fused: xs(fp16) = z * dinv; block 0 zeros both dummy rows. ----
__global__ __launch_bounds__(1024) void k_build(const int* __restrict__ btot,
                                                const int* __restrict__ ebuf,
                                                int* __restrict__ col,
                                                int2* __restrict__ rowinfo,
                                                float* __restrict__ dinv,
                                                const float* __restrict__ z,
                                                u16* __restrict__ xs,
                                                u16* __restrict__ xs_other) {
    __shared__ int deg[BUCKET_NODES];
    __shared__ int cur[BUCKET_NODES];
    __shared__ int sm[512];
    __shared__ int cls[CAP_C];
    int b = blockIdx.x, t = threadIdx.x;
    int nb = b * BUCKET_NODES;
    int nn = N_NODES - nb < BUCKET_NODES ? N_NODES - nb : BUCKET_NODES;
    int ne = btot[b];
    const int* eb = ebuf + b * CAP_E;

    for (int i = t; i < BUCKET_NODES; i += 1024) deg[i] = 0;
    __syncthreads();
    for (int e = t; e < ne; e += 1024) atomicAdd(&deg[eb[e] >> 17], 1);
    __syncthreads();

    // pad-to-16 lengths, inclusive Hillis-Steele scan over 512 slots (nn<512)
    int v = (t < nn) ? ((deg[t] + 15) & ~15) : 0;
    if (t < 512) sm[t] = v;
    __syncthreads();
    for (int off = 1; off < 512; off <<= 1) {
        int u = (t >= off && t < 512) ? sm[t - off] : 0;
        __syncthreads();
        if (t < 512) sm[t] += u;
        __syncthreads();
    }
    int total = sm[511];
    int colbase = b * CAP_C;
    if (t < nn) {
        int off0 = sm[t] - v;
        cur[t] = off0;
        rowinfo[nb + t] = make_int2(colbase + off0, v);
        dinv[nb + t] = rsqrtf((float)deg[t] + 1.0f);
    }
    __syncthreads();
    for (int i = t; i < total; i += 1024) cls[i] = DUMMY;  // pads pre-filled
    __syncthreads();
    for (int e = t; e < ne; e += 1024) {
        int pe = eb[e];
        int l = atomicAdd(&cur[pe >> 17], 1);
        cls[l] = pe & 0x1FFFF;
    }
    __syncthreads();
    for (int i = t; i < total; i += 1024) col[colbase + i] = cls[i];

    // fused scale: xs(fp16) = z * dinv for this bucket's rows
    const float4* zz = (const float4*)(z + (size_t)nb * 64);
    uint2* xx = (uint2*)(xs + (size_t)nb * 64);
    for (int i = t; i < nn * 16; i += 1024) {
        float4 vv = zz[i];
        float dd = rsqrtf((float)deg[i >> 4] + 1.0f);
        unsigned p0 = (unsigned)f2h(vv.x * dd) | ((unsigned)f2h(vv.y * dd) << 16);
        unsigned p1 = (unsigned)f2h(vv.z * dd) | ((unsigned)f2h(vv.w * dd) << 16);
        xx[i] = make_uint2(p0, p1);
    }
    if (b == 0 && t < 8) {  // zero dummy rows of both fp16 feature buffers
        ((uint4*)(xs + (size_t)N_NODES * 64))[t] = make_uint4(0, 0, 0, 0);
        ((uint4*)(xs_other + (size_t)N_NODES * 64))[t] = make_uint4(0, 0, 0, 0);
    }
}

// ---- fused layer, cross-node software-pipelined:
//      h = dinv[d]*(sum_{s in row(d)} xs[s] + xs[d]); out = epi(h @ W + b).
//      Next node's rowinfo/col/first-16-slot gathers issue BEFORE the
//      current node's butterfly+matvec epilogue -> epilogue hides the
//      next chain's memory latency. fp16 rows (128 B = 8 lanes x uint4). ----
__global__ __launch_bounds__(256) void k_layer(const int2* __restrict__ rowinfo,
                                               const int* __restrict__ col,
                                               const float* __restrict__ dinv,
                                               const u16* __restrict__ xs,
                                               const float* __restrict__ W,
                                               const float* __restrict__ bias,
                                               u16* __restrict__ outh,
                                               float* __restrict__ outf,
                                               int hidden) {
    const int lane = threadIdx.x & 63;
    const int eighth = lane >> 3;   // slot pair selector within 16-slot iter
    const int fh = lane & 7;        // which uint4 (8 features) of the row

    float wcol[64];
#pragma unroll
    for (int k = 0; k < 64; ++k) wcol[k] = W[k * 64 + lane];
    const float bv = bias[lane];

    int wave = (blockIdx.x * blockDim.x + threadIdx.x) >> 6;
    int nwaves = (gridDim.x * blockDim.x) >> 6;

    int node = wave;
    if (node >= N_NODES) return;
    int un = __builtin_amdgcn_readfirstlane(node);
    int2 ri = rowinfo[un];
    int2 ii = *(const int2*)(col + ri.x + 2 * eighth);
    uint4 qa = *(const uint4*)(xs + (size_t)ii.x * 64 + fh * 8);
    uint4 qb = *(const uint4*)(xs + (size_t)ii.y * 64 + fh * 8);

    while (true) {
        float acc[8] = {0.f, 0.f, 0.f, 0.f, 0.f, 0.f, 0.f, 0.f};
        acc8(acc, qa);
        acc8(acc, qb);
        int iters = ri.y >> 4;
        for (int r = 1; r < iters; ++r) {  // wave-uniform trip count
            int2 j2 = *(const int2*)(col + ri.x + (r << 4) + 2 * eighth);
            uint4 q2 = *(const uint4*)(xs + (size_t)j2.x * 64 + fh * 8);
            uint4 q3 = *(const uint4*)(xs + (size_t)j2.y * 64 + fh * 8);
            acc8(acc, q2);
            acc8(acc, q3);
        }
        // issue self-row + dinv loads early (consumed after butterfly)
        uint4 qs = *(const uint4*)(xs + (size_t)un * 64 + fh * 8);
        float di = dinv[un];

        // ---- prefetch next node's first block (wave-uniform guard) ----
        int nnode = node + nwaves;
        bool more = (nnode < N_NODES);
        int un_n = un;
        int2 ri_n = ri;
        uint4 qa_n = make_uint4(0, 0, 0, 0), qb_n = make_uint4(0, 0, 0, 0);
        if (more) {
            un_n = __builtin_amdgcn_readfirstlane(nnode);
            ri_n = rowinfo[un_n];
            int2 ii_n = *(const int2*)(col + ri_n.x + 2 * eighth);
            qa_n = *(const uint4*)(xs + (size_t)ii_n.x * 64 + fh * 8);
            qb_n = *(const uint4*)(xs + (size_t)ii_n.y * 64 + fh * 8);
        }

        // ---- epilogue for `node` (overlaps prefetch latency) ----
#pragma unroll
        for (int m = 8; m <= 32; m <<= 1) {
#pragma unroll
            for (int j = 0; j < 8; ++j) acc[j] += __shfl_xor(acc[j], m, 64);
        }
        {
            float s[8] = {0.f, 0.f, 0.f, 0.f, 0.f, 0.f, 0.f, 0.f};
            acc8(s, qs);
#pragma unroll
            for (int j = 0; j < 8; ++j) acc[j] = (acc[j] + s[j]) * di;
        }
        float o0 = bv, o1 = 0.f;
#pragma unroll
        for (int k = 0; k < 64; k += 2) {
            o0 = fmaf(bcast_lane(acc[k & 7], k >> 3), wcol[k], o0);
            o1 = fmaf(bcast_lane(acc[(k + 1) & 7], (k + 1) >> 3), wcol[k + 1], o1);
        }
        float o = o0 + o1;
        if (hidden) {
            o = fmaxf(o, 0.f) * di;  // pre-scale for next layer's gather
            outh[(size_t)un * 64 + lane] = f2h(o);
        } else {
            outf[(size_t)un * 64 + lane] = o;
        }

        if (!more) break;
        node = nnode;
        un = un_n;
        ri = ri_n;
        qa = qa_n;
        qb = qb_n;
    }
}

extern "C" void kernel_launch(void* const* d_in, const int* in_sizes, int n_in,
                              void* d_out, int out_size, void* d_ws, size_t ws_size,
                              hipStream_t stream) {
    const float* z  = (const float*)d_in[0];
    const int* src  = (const int*)d_in[1];
    const int* dst  = (const int*)d_in[2];
    const float* W1 = (const float*)d_in[3];
    const float* b1 = (const float*)d_in[4];
    const float* W2 = (const float*)d_in[5];
    const float* b2 = (const float*)d_in[6];
    const float* W3 = (const float*)d_in[7];
    const float* b3 = (const float*)d_in[8];
    float* out = (float*)d_out;

    char* p = (char*)d_ws;
    float* dinv    = (float*)p;  p += (size_t)512 << 10;
    int2*  rowinfo = (int2*)p;   p += (size_t)1 << 20;                    // 800 KB used
    int*   btot    = (int*)p;    p += (size_t)4 << 10;
    int*   ebuf    = (int*)p;    p += (size_t)N_BUCKETS * CAP_E * 4;      // 8 MB
    int*   col     = (int*)p;    p += (size_t)N_BUCKETS * CAP_C * 4;      // 12.6 MB
    u16*   buf0    = (u16*)p;    p += (size_t)14 << 20;                   // 12.8 MB used
    u16*   buf1    = (u16*)p;                                             // 12.8 MB

    const int gL = 2048;  // 8192 waves

    // ---- CSR build + fp16 scale: 3 dispatches ----
    hipMemsetAsync(btot, 0, N_BUCKETS * sizeof(int), stream);
    k_bucket<<<BKT_BLOCKS, 256, 0, stream>>>(src, dst, btot, ebuf);
    k_build<<<N_BUCKETS, 1024, 0, stream>>>(btot, ebuf, col, rowinfo, dinv, z, buf0, buf1);

    // ---- 3 fused layers ----
    k_layer<<<gL, 256, 0, stream>>>(rowinfo, col, dinv, buf0, W1, b1, buf1, nullptr, 1);
    k_layer<<<gL, 256, 0, stream>>>(rowinfo, col, dinv, buf1, W2, b2, buf0, nullptr, 1);
    k_layer<<<gL, 256, 0, stream>>>(rowinfo, col, dinv, buf0, W3, b3, nullptr, out, 0);
}